// Round 18
// baseline (1472.232 us; speedup 1.0000x reference)
//
#include <hip/hip_runtime.h>
#include <cstdint>

#define B 16
#define TY 1600
#define TX 400
#define MAS 384
#define HID 768
#define NEGV -1e9f

typedef __bf16 bf16x8 __attribute__((ext_vector_type(8)));
typedef float  f32x4  __attribute__((ext_vector_type(4)));
typedef float  f32x16 __attribute__((ext_vector_type(16)));

__device__ __forceinline__ f32x4 mfma16(bf16x8 a, bf16x8 b, f32x4 c) {
  return __builtin_amdgcn_mfma_f32_16x16x32_bf16(a, b, c, 0, 0, 0);
}
__device__ __forceinline__ f32x16 mfma32(bf16x8 a, bf16x8 b, f32x16 c) {
  return __builtin_amdgcn_mfma_f32_32x32x16_bf16(a, b, c, 0, 0, 0);
}

// ---------------- fp32 -> bf16 hi/lo split with channel padding ----------------
__global__ void split_pad_k(const float* __restrict__ in, __bf16* __restrict__ oh,
                            __bf16* __restrict__ ol, int CIN, int CINP, long n) {
  long i = (long)blockIdx.x * 256 + threadIdx.x;
  if (i >= n) return;
  long row = i / CINP; int ci = (int)(i - row * CINP);
  float v = (ci < CIN) ? in[row * CIN + ci] : 0.f;
  __bf16 h = (__bf16)v;
  oh[i] = h; ol[i] = (__bf16)(v - (float)h);
}

// ---------------- weight repack+split: w[N][CIN][K] -> oh/ol[N][k*CINP + ci] ----------------
__global__ void wsplit_k(const float* __restrict__ w, __bf16* __restrict__ oh,
                         __bf16* __restrict__ ol, int CIN, int K_, int CINP, long n) {
  long i = (long)blockIdx.x * 256 + threadIdx.x;
  if (i >= n) return;
  long kdspan = (long)K_ * CINP;
  long nn = i / kdspan; int kd = (int)(i - nn * kdspan);
  int k = kd / CINP, ci = kd - k * CINP;
  float v = (ci < CIN) ? w[(nn * CIN + ci) * K_ + k] : 0.f;
  __bf16 h = (__bf16)v;
  oh[i] = h; ol[i] = (__bf16)(v - (float)h);
}

// ---------------- transpose+split: w2 [m][JTOT] -> oh/ol [j][384] ----------------
__global__ void tsplit_k(const float* __restrict__ in, __bf16* __restrict__ oh,
                         __bf16* __restrict__ ol, int JTOT, long n) {
  long i = (long)blockIdx.x * 256 + threadIdx.x;
  if (i >= n) return;
  int m = (int)(i / JTOT), j = (int)(i - (long)m * JTOT);
  float v = in[i];
  long o = (long)j * 384 + m;
  __bf16 h = (__bf16)v;
  oh[o] = h; ol[o] = (__bf16)(v - (float)h);
}

// ---------------- bias fold: o[n] = sum_m wq[n][m] * b[m] ----------------
__global__ void fold_bias_k(const float* __restrict__ wq, const float* __restrict__ b,
                            float* __restrict__ o) {
  int n = threadIdx.x;
  float s = 0.f;
  for (int m = 0; m < 384; ++m) s = fmaf(wq[n * 384 + m], b[m], s);
  o[n] = s;
}

// ---------------- weight-fold GEMM (conv2-staging-native output layout) ----------------
template<int KK>
__global__ __launch_bounds__(256)
void fold_mfma(const __bf16* __restrict__ xh, const __bf16* __restrict__ xl,
               const __bf16* __restrict__ wh, const __bf16* __restrict__ wl,
               __bf16* __restrict__ oh, __bf16* __restrict__ ol)
{
  constexpr int CINP = 384, ROWS = 64, STRIDE = 65;
  __shared__ float4 xs[8 * STRIDE];
  const int t0 = blockIdx.x * 64, n0 = blockIdx.y * 128;
  const int tid = threadIdx.x, wn = tid >> 6, lane = tid & 63;
  const int lr = lane & 15, lg = lane >> 4;
  const f32x4 Z4 = {0.f, 0.f, 0.f, 0.f};
  f32x4 acc[4][2];
  #pragma unroll
  for (int m = 0; m < 4; ++m) { acc[m][0] = Z4; acc[m][1] = Z4; }

  #pragma unroll 1
  for (int ci0 = 0; ci0 < CINP; ci0 += 32) {
    __syncthreads();
    for (int e = tid; e < ROWS * 8; e += 256) {
      int row = e >> 3, sc = e & 7, spl = sc >> 2, cg = sc & 3;
      int t = t0 + row;
      xs[(spl * 4 + cg) * STRIDE + row] =
          *(const float4*)((spl ? xl : xh) + (size_t)t * CINP + ci0 + cg * 8);
    }
    __syncthreads();
    bf16x8 ah[4], al[4];
    #pragma unroll
    for (int mf = 0; mf < 4; ++mf) {
      int row = mf * 16 + lr;
      ah[mf] = *(const bf16x8*)&xs[lg * STRIDE + row];
      al[mf] = *(const bf16x8*)&xs[(4 + lg) * STRIDE + row];
    }
    size_t kd = (size_t)ci0 + lg * 8;
    bf16x8 bh[2], bl[2];
    #pragma unroll
    for (int nf = 0; nf < 2; ++nf) {
      int nc = n0 + wn * 32 + nf * 16 + lr;
      bh[nf] = *(const bf16x8*)(wh + (size_t)nc * 384 + kd);
      bl[nf] = *(const bf16x8*)(wl + (size_t)nc * 384 + kd);
    }
    #pragma unroll
    for (int nf = 0; nf < 2; ++nf)
      #pragma unroll
      for (int mf = 0; mf < 4; ++mf) acc[mf][nf] = mfma16(ah[mf], bh[nf], acc[mf][nf]);
    #pragma unroll
    for (int nf = 0; nf < 2; ++nf)
      #pragma unroll
      for (int mf = 0; mf < 4; ++mf) acc[mf][nf] = mfma16(ah[mf], bl[nf], acc[mf][nf]);
    #pragma unroll
    for (int nf = 0; nf < 2; ++nf)
      #pragma unroll
      for (int mf = 0; mf < 4; ++mf) acc[mf][nf] = mfma16(al[mf], bh[nf], acc[mf][nf]);
  }
  #pragma unroll
  for (int nf = 0; nf < 2; ++nf) {
    int c = n0 + wn * 32 + nf * 16 + lr;
    #pragma unroll
    for (int mf = 0; mf < 4; ++mf) {
      #pragma unroll
      for (int r = 0; r < 4; ++r) {
        int j = t0 + mf * 16 + lg * 4 + r;   // j = ci*KK + k
        int k = j % KK, ci = j / KK;
        size_t o = (size_t)((((ci >> 4) * KK + k) * 2 + ((ci >> 3) & 1)) * 3072)
                 + (size_t)c * 8 + (ci & 7);
        float v = acc[mf][nf][r];
        __bf16 vh = (__bf16)v;
        oh[o] = vh; ol[o] = (__bf16)(v - (float)vh);
      }
    }
  }
}

// ---------------- conv1 + ReGLU, split-bf16 MFMA ----------------
template<int CINP, int K, int T>
__global__ __launch_bounds__(256)
void conv1_mfma(const __bf16* __restrict__ xh, const __bf16* __restrict__ xl,
                const __bf16* __restrict__ wh, const __bf16* __restrict__ wl,
                const float* __restrict__ bias, const int* __restrict__ lens,
                __bf16* __restrict__ hh, __bf16* __restrict__ hl)
{
  constexpr int BM = 128, PAD = K / 2, ROWS = BM + K - 1, KD = K * CINP;
  __shared__ float4 xs[8 * ROWS];
  const int b = blockIdx.z, t0 = blockIdx.x * BM, n0 = blockIdx.y * 64;
  const int tid = threadIdx.x, wid = tid >> 6, lane = tid & 63;
  const int wm = wid >> 1, wn = wid & 1, lr = lane & 15, lg = lane >> 4;
  const int len = lens[b];
  const f32x4 Z4 = {0.f, 0.f, 0.f, 0.f};
  f32x4 acc_a[4][2], acc_g[4][2];
  #pragma unroll
  for (int m = 0; m < 4; ++m)
    #pragma unroll
    for (int n = 0; n < 2; ++n) { acc_a[m][n] = Z4; acc_g[m][n] = Z4; }

  #pragma unroll 1
  for (int ci0 = 0; ci0 < CINP; ci0 += 32) {
    __syncthreads();
    for (int e = tid; e < ROWS * 8; e += 256) {
      int row = e >> 3, sc = e & 7, spl = sc >> 2, cg = sc & 3;
      int t = t0 + row - PAD;
      float4 v = {0.f, 0.f, 0.f, 0.f};
      if (t >= 0 && t < len)
        v = *(const float4*)((spl ? xl : xh) + ((size_t)b * T + t) * CINP + ci0 + cg * 8);
      xs[(spl * 4 + cg) * ROWS + row] = v;
    }
    __syncthreads();
    #pragma unroll
    for (int k = 0; k < K; ++k) {
      bf16x8 ah[4], al[4];
      #pragma unroll
      for (int mf = 0; mf < 4; ++mf) {
        int row = wm * 64 + mf * 16 + lr + k;
        ah[mf] = *(const bf16x8*)&xs[lg * ROWS + row];
        al[mf] = *(const bf16x8*)&xs[(4 + lg) * ROWS + row];
      }
      size_t kd = (size_t)k * CINP + ci0 + lg * 8;
      #pragma unroll
      for (int nf = 0; nf < 2; ++nf) {
        int na = n0 + wn * 32 + nf * 16 + lr;
        bf16x8 bah = *(const bf16x8*)(wh + (size_t)na * KD + kd);
        bf16x8 bal = *(const bf16x8*)(wl + (size_t)na * KD + kd);
        bf16x8 bgh = *(const bf16x8*)(wh + (size_t)(na + HID) * KD + kd);
        bf16x8 bgl = *(const bf16x8*)(wl + (size_t)(na + HID) * KD + kd);
        #pragma unroll
        for (int mf = 0; mf < 4; ++mf) {
          acc_a[mf][nf] = mfma16(ah[mf], bah, acc_a[mf][nf]);
          acc_a[mf][nf] = mfma16(ah[mf], bal, acc_a[mf][nf]);
          acc_a[mf][nf] = mfma16(al[mf], bah, acc_a[mf][nf]);
          acc_g[mf][nf] = mfma16(ah[mf], bgh, acc_g[mf][nf]);
          acc_g[mf][nf] = mfma16(ah[mf], bgl, acc_g[mf][nf]);
          acc_g[mf][nf] = mfma16(al[mf], bgh, acc_g[mf][nf]);
        }
      }
    }
  }
  #pragma unroll
  for (int nf = 0; nf < 2; ++nf) {
    int c = n0 + wn * 32 + nf * 16 + lr;
    float ba = bias[c], bg = bias[c + HID];
    #pragma unroll
    for (int mf = 0; mf < 4; ++mf) {
      #pragma unroll
      for (int r = 0; r < 4; ++r) {
        int t = t0 + wm * 64 + mf * 16 + lg * 4 + r;
        if (t < T) {
          float a = acc_a[mf][nf][r] + ba;
          float g = acc_g[mf][nf][r] + bg;
          float v = a * fmaxf(g, 0.f);
          __bf16 vh = (__bf16)v;
          size_t o = ((size_t)b * T + t) * HID + c;
          hh[o] = vh;
          hl[o] = (__bf16)(v - (float)vh);
        }
      }
    }
  }
}

// ---------------- conv2 (folded weights), 32x32x16, B staged in LDS via global_load_lds ----------------
template<int K, int T, bool STORET>
__global__ __launch_bounds__(256)
void conv2_mfma(const __bf16* __restrict__ xh, const __bf16* __restrict__ xl,
                const __bf16* __restrict__ wh, const __bf16* __restrict__ wl,
                const float* __restrict__ bias, const float* __restrict__ ab,
                const int* __restrict__ lens, float* __restrict__ out)
{
  constexpr int CINP = 768, BM = 128, PAD = K / 2, ROWS = BM + K - 1, STRIDE = ROWS + 1;
  constexpr int BROWS = K * 2;
  __shared__ float4 xa[4 * STRIDE];
  __shared__ float4 bs[2 * BROWS * 192];
  const int b = blockIdx.z, t0 = blockIdx.x * BM, n0 = blockIdx.y * 192;
  const int tid = threadIdx.x, wid = tid >> 6, lane = tid & 63;
  const int wm = wid >> 1, wn = wid & 1, lc = lane & 31, lk = lane >> 5;
  const int len = lens[b];
  f32x16 acc[2][3];
  #pragma unroll
  for (int m = 0; m < 2; ++m)
    #pragma unroll
    for (int n = 0; n < 3; ++n)
      #pragma unroll
      for (int r = 0; r < 16; ++r) acc[m][n][r] = 0.f;

  #pragma unroll 1
  for (int s = 0; s < 48; ++s) {
    __syncthreads();
    for (int e = tid; e < ROWS * 4; e += 256) {
      int row = e >> 2, sc = e & 3, spl = sc >> 1, cg = sc & 1;
      int t = t0 + row - PAD;
      float4 v = {0.f, 0.f, 0.f, 0.f};
      if (t >= 0 && t < len)
        v = *(const float4*)((spl ? xl : xh) + ((size_t)b * T + t) * CINP + s * 16 + cg * 8);
      xa[(spl * 2 + cg) * STRIDE + row] = v;
    }
    for (int r = wid; r < 2 * BROWS; r += 4) {
      int spl = r / BROWS, rr = r - spl * BROWS;
      const char* src = (const char*)((spl ? wl : wh) + (size_t)(s * BROWS + rr) * 3072
                                      + (size_t)n0 * 8) + (size_t)lane * 16;
      char* dst = (char*)&bs[r * 192];
      #pragma unroll
      for (int i = 0; i < 3; ++i)
        __builtin_amdgcn_global_load_lds(
            (const __attribute__((address_space(1))) void*)(src + i * 1024),
            (__attribute__((address_space(3))) void*)(dst + i * 1024), 16, 0, 0);
    }
    __syncthreads();
    #pragma unroll
    for (int k = 0; k < K; ++k) {
      bf16x8 ah[2], al[2], bh[3], bl[3];
      #pragma unroll
      for (int mf = 0; mf < 2; ++mf) {
        int row = wm * 64 + mf * 32 + lc + k;
        ah[mf] = *(const bf16x8*)&xa[lk * STRIDE + row];
        al[mf] = *(const bf16x8*)&xa[(2 + lk) * STRIDE + row];
      }
      #pragma unroll
      for (int nf = 0; nf < 3; ++nf) {
        int col = wn * 96 + nf * 32 + lc;
        bh[nf] = *(const bf16x8*)&bs[(k * 2 + lk) * 192 + col];
        bl[nf] = *(const bf16x8*)&bs[(BROWS + k * 2 + lk) * 192 + col];
      }
      #pragma unroll
      for (int nf = 0; nf < 3; ++nf)
        #pragma unroll
        for (int mf = 0; mf < 2; ++mf)
          acc[mf][nf] = mfma32(ah[mf], bh[nf], acc[mf][nf]);
      #pragma unroll
      for (int nf = 0; nf < 3; ++nf)
        #pragma unroll
        for (int mf = 0; mf < 2; ++mf)
          acc[mf][nf] = mfma32(ah[mf], bl[nf], acc[mf][nf]);
      #pragma unroll
      for (int nf = 0; nf < 3; ++nf)
        #pragma unroll
        for (int mf = 0; mf < 2; ++mf)
          acc[mf][nf] = mfma32(al[mf], bh[nf], acc[mf][nf]);
    }
  }
  #pragma unroll
  for (int nf = 0; nf < 3; ++nf) {
    int c = n0 + wn * 96 + nf * 32 + lc;
    float bb = bias[c], aB = ab[c];
    #pragma unroll
    for (int mf = 0; mf < 2; ++mf) {
      #pragma unroll
      for (int r = 0; r < 16; ++r) {
        int t = t0 + wm * 64 + mf * 32 + (r & 3) + 8 * (r >> 2) + 4 * lk;
        if (t < T) {
          float v = acc[mf][nf][r] + bb;
          if (t >= len) v = 0.f;
          v += aB;
          if (STORET) out[((size_t)b * MAS + c) * T + t] = v;
          else        out[((size_t)b * T + t) * MAS + c] = v;
        }
      }
    }
  }
}

// ---------------- scores + softmax + safe_log ----------------
__global__ __launch_bounds__(512)
void scores_k(const float* __restrict__ q, const float* __restrict__ kT,
              const int* __restrict__ xl, const int* __restrict__ yl,
              float* __restrict__ oattn, float* __restrict__ ologp)
{
  __shared__ float qs[16 * 384];
  __shared__ float tmp[8];
  const int b = blockIdx.y, y0 = blockIdx.x * 16, tid = threadIdx.x;
  for (int e = tid; e < 16 * 384; e += 512)
    qs[e] = q[((size_t)b * TY + (y0 + e / 384)) * 384 + (e - (e / 384) * 384)];
  __syncthreads();
  float acc[16];
  #pragma unroll
  for (int i = 0; i < 16; ++i) acc[i] = 0.f;
  const int x = tid;
  if (x < TX) {
    const float* kb = kT + (size_t)b * MAS * TX + x;
    for (int d = 0; d < 384; d += 4) {
      float k0 = kb[(size_t)(d + 0) * TX], k1 = kb[(size_t)(d + 1) * TX];
      float k2 = kb[(size_t)(d + 2) * TX], k3 = kb[(size_t)(d + 3) * TX];
      #pragma unroll
      for (int yy = 0; yy < 16; ++yy) {
        float4 qv = *(const float4*)&qs[yy * 384 + d];
        acc[yy] = fmaf(qv.x, k0, fmaf(qv.y, k1, fmaf(qv.z, k2, fmaf(qv.w, k3, acc[yy]))));
      }
    }
  }
  const int xlen = xl[b], ylen = yl[b];
  const float scale = 0.05103103630798288f;
  const bool xpad = (x >= xlen);
  const int wv = tid >> 6, ln = tid & 63;
  #pragma unroll 1
  for (int yy = 0; yy < 16; ++yy) {
    int y = y0 + yy;
    float s = -3.0e38f;
    if (x < TX) {
      s = acc[yy] * scale;
      if (xpad && (y >= ylen)) s = -1e-9f;
    }
    float m = s;
    for (int off = 32; off; off >>= 1) m = fmaxf(m, __shfl_xor(m, off));
    if (ln == 0) tmp[wv] = m;
    __syncthreads();
    float mx = fmaxf(fmaxf(fmaxf(tmp[0], tmp[1]), fmaxf(tmp[2], tmp[3])),
                     fmaxf(fmaxf(tmp[4], tmp[5]), fmaxf(tmp[6], tmp[7])));
    __syncthreads();
    float e = (x < TX) ? expf(s - mx) : 0.f;
    float sm = e;
    for (int off = 32; off; off >>= 1) sm += __shfl_xor(sm, off);
    if (ln == 0) tmp[wv] = sm;
    __syncthreads();
    float tot = tmp[0] + tmp[1] + tmp[2] + tmp[3] + tmp[4] + tmp[5] + tmp[6] + tmp[7];
    __syncthreads();
    if (x < TX) {
      float w = e / tot;
      size_t o = ((size_t)b * TY + y) * TX + x;
      oattn[o] = w;
      ologp[o] = logf(w + 1e-6f);
    }
  }
}

// ---------------- MAS forward: 4-wave super-wave DP, halo-8 (2 exchanges / 16 rows),
//                  bits -> global u64 per 8 rows ----------------
#define LBAR() do {                                                       \
    asm volatile("s_waitcnt lgkmcnt(0)" ::: "memory");                    \
    __builtin_amdgcn_sched_barrier(0);                                    \
    __builtin_amdgcn_s_barrier();                                         \
    __builtin_amdgcn_sched_barrier(0); } while (0)

#define MLD8(h0_, Lb) do {                                                \
    _Pragma("unroll")                                                     \
    for (int r_ = 0; r_ < 8; ++r_) {                                      \
      const int row_ = (h0_) + r_;                                        \
      _Pragma("unroll")                                                   \
      for (int i_ = 0; i_ < 5; ++i_)                                      \
        Lb[r_][i_] = *(const float2*)&half[row_ * 400 + a[i_]];           \
    } } while (0)

#define MCMP8(h0_, Lb) do {                                               \
    _Pragma("unroll")                                                     \
    for (int r_ = 0; r_ < 8; ++r_) {                                      \
      const int y_ = ybase + (h0_) + r_;                                  \
      float lp[10];                                                       \
      _Pragma("unroll")                                                   \
      for (int i_ = 0; i_ < 5; ++i_) {                                    \
        lp[2 * i_]     = Lb[r_][i_].x + wxm[2 * i_];                      \
        lp[2 * i_ + 1] = Lb[r_][i_].y + wxm[2 * i_ + 1];                  \
      }                                                                   \
      if (phase1) {                                                       \
        int c_ = y_ - p0;                                                 \
        _Pragma("unroll")                                                 \
        for (int j_ = 0; j_ < 10; ++j_) lp[j_] = (j_ <= c_) ? lp[j_] : NEGV; \
      }                                                                   \
      unsigned pr_ = ((w[7] > w[8]) ? 1u : 0u) | ((w[8] > w[9]) ? 2u : 0u); \
      p16 |= pr_ << ((y_ & 7) * 2);                                       \
      float nw[10];                                                       \
      nw[0] = lp[0] + w[0];                                               \
      _Pragma("unroll")                                                   \
      for (int j_ = 1; j_ < 10; ++j_) nw[j_] = lp[j_] + fmaxf(w[j_], w[j_ - 1]); \
      _Pragma("unroll")                                                   \
      for (int j_ = 0; j_ < 10; ++j_) w[j_] = nw[j_];                     \
    } } while (0)

#define FLUSHBITS(y7_) do {                                               \
    unsigned lo = 0, hi = 0;                                              \
    _Pragma("unroll")                                                     \
    for (int r2_ = 0; r2_ < 4; ++r2_) {                                   \
      lo |= ((p16 >> (2 * r2_)) & 3u) << (8 * r2_);                       \
      hi |= ((p16 >> (2 * r2_ + 8)) & 3u) << (8 * r2_);                   \
    }                                                                     \
    unsigned lo1 = (unsigned)__shfl_xor((int)lo, 1), hi1 = (unsigned)__shfl_xor((int)hi, 1); \
    lo |= lo1 << 2; hi |= hi1 << 2;                                       \
    unsigned lo2 = (unsigned)__shfl_xor((int)lo, 2), hi2 = (unsigned)__shfl_xor((int)hi, 2); \
    lo |= lo2 << 4; hi |= hi2 << 4;                                       \
    if ((GL & 3) == 0 && GL < 200) {                                      \
      unsigned long long E = (unsigned long long)lo | ((unsigned long long)hi << 32); \
      *(unsigned long long*)&bb8[(size_t)((y7_) >> 3) * 512 + (size_t)(GL >> 2) * 8] = E; \
    }                                                                     \
    p16 = 0; } while (0)

#define PUBEX() do {                                                      \
    if (GL < 200) { vbuf[pb][2 * GL] = w[8]; vbuf[pb][2 * GL + 1] = w[9]; } \
    LBAR();                                                               \
    _Pragma("unroll")                                                     \
    for (int j_ = 0; j_ < 8; ++j_) {                                      \
      int x_ = p0 + j_;                                                   \
      w[j_] = (x_ >= 0 && GL < 200) ? vbuf[pb][x_] : NEGV;                \
    }                                                                     \
    pb ^= 1; } while (0)

__global__ __launch_bounds__(256, 1)
void mas_fwd(const float* __restrict__ logprob, const int* __restrict__ xl,
             const int* __restrict__ yl, unsigned char* __restrict__ bits)
{
  __shared__ float ring[12800];              // 2 slots x 16 rows x 400 floats
  __shared__ float vbuf[2][400];             // boundary-exchange rows
  const int b = blockIdx.x;
  const int tid = threadIdx.x, wid = tid >> 6, lane = tid & 63;
  const int GL = tid;                        // owns x = 2GL, 2GL+1
  const int xlen = xl[b], ylen = yl[b];
  const float* lpb = logprob + (size_t)b * TY * TX;
  unsigned char* bb8 = bits + (size_t)b * 102400;   // [yblk 200][byte 64][8 rows]
  const int p0 = GL * 2 - 8;                 // leftmost halo position (halo = 8)

  int a[5];
  #pragma unroll
  for (int i = 0; i < 5; ++i) {
    int t = p0 + 2 * i;
    a[i] = t < 0 ? 0 : (t > 398 ? 398 : t);
  }

  float w[10], wxm[10];
  #pragma unroll
  for (int j = 0; j < 10; ++j) {
    int x = p0 + j;
    wxm[j] = (x >= 0 && x < xlen) ? 0.f : NEGV;
    w[j] = (x == 0) ? 0.f : NEGV;
  }

  const char* lpc = (const char*)lpb;
  constexpr size_t maxgs = (size_t)TY * 1600 - 25600;
  char* ringc = (char*)ring;
  auto issue_group = [&](int g) {
    size_t gs = (size_t)g * 25600; if (gs > maxgs) gs = maxgs;
    for (int c = wid; c < 25; c += 4)
      __builtin_amdgcn_global_load_lds(
          (const __attribute__((address_space(1))) void*)(lpc + gs + (size_t)c * 1024 + (size_t)lane * 16),
          (__attribute__((address_space(3))) void*)(ringc + (g & 1) * 25600 + c * 1024), 16, 0, 0);
  };

  issue_group(0);
  issue_group(1);

  int pb = 0;
  unsigned p16 = 0;
  const int ngroups = (ylen + 15) >> 4;
  #pragma unroll 1
  for (int g = 0; g < ngroups; ++g) {
    // counted per-wave vmem wait (group g landed; g+1 in flight; bit-stores are old)
    if (wid == 0) asm volatile("s_waitcnt vmcnt(7)" ::: "memory");
    else          asm volatile("s_waitcnt vmcnt(6)" ::: "memory");
    __builtin_amdgcn_sched_barrier(0);
    __builtin_amdgcn_s_barrier();
    __builtin_amdgcn_sched_barrier(0);
    const float* half = ring + (g & 1) * 6400;
    const int ybase = g * 16;
    const bool phase1 = (ybase < TX);
    float2 L[8][5];
    // half A: rows 0-7
    MLD8(0, L);
    MCMP8(0, L);
    FLUSHBITS(ybase + 7);
    PUBEX();
    // half B: rows 8-15
    MLD8(8, L);
    MCMP8(8, L);
    FLUSHBITS(ybase + 15);
    PUBEX();
    __builtin_amdgcn_sched_barrier(0);
    issue_group(g + 2);
  }
}

// ---------------- MAS backtrack: global bits, uniform scalar walk via readlane ----------------
__global__ __launch_bounds__(64)
void mas_bt(const unsigned char* __restrict__ bits, const int* __restrict__ xl,
            const int* __restrict__ yl, float* __restrict__ hard, float* __restrict__ dur)
{
  const int b = blockIdx.x;
  const int lane = threadIdx.x;
  const int xlen = xl[b], ylen = yl[b];
  const unsigned char* bb8 = bits + (size_t)b * 102400;
  float* hb = hard + (size_t)b * TX * TY;
  float* db = dur + (size_t)b * TX;

  int x = xlen - 1;
  int cnt = 0;
  #pragma unroll 1
  for (int ycur = ylen - 1; ycur >= 0; ycur -= 64) {
    int lo = x - 63; if (lo < 0) lo = 0;
    const int wb = (lo >> 3) & ~3;                  // window bytes [wb, wb+12)
    int ry = ycur - lane;
    unsigned w0 = 0, w1 = 0, w2 = 0;
    if (ry >= 0) {
      const unsigned char* p = bb8 + (size_t)(ry >> 3) * 512 + (ry & 7);
      unsigned bt_[12];
      #pragma unroll
      for (int j = 0; j < 12; ++j) bt_[j] = p[(size_t)(wb + j) * 8];
      w0 = bt_[0] | (bt_[1] << 8) | (bt_[2] << 16) | (bt_[3] << 24);
      w1 = bt_[4] | (bt_[5] << 8) | (bt_[6] << 16) | (bt_[7] << 24);
      w2 = bt_[8] | (bt_[9] << 8) | (bt_[10] << 16) | (bt_[11] << 24);
    }
    const int rows = (ycur + 1 < 64) ? (ycur + 1) : 64;
    #pragma unroll 1
    for (int s = 0; s < rows; s += 8) {
      const int cnt8 = (rows - s < 8) ? (rows - s) : 8;
      unsigned r0[8], r1[8], r2[8];
      #pragma unroll
      for (int u = 0; u < 8; ++u) {
        r0[u] = (unsigned)__builtin_amdgcn_readlane((int)w0, s + u);
        r1[u] = (unsigned)__builtin_amdgcn_readlane((int)w1, s + u);
        r2[u] = (unsigned)__builtin_amdgcn_readlane((int)w2, s + u);
      }
      #pragma unroll
      for (int u = 0; u < 8; ++u) {
        if (u < cnt8) {
          const int yy = ycur - s - u;
          ++cnt;
          if (yy > 0 && x > 0) {
            const int boff = (x >> 3) - wb;
            const unsigned word = (boff < 4) ? r0[u] : ((boff < 8) ? r1[u] : r2[u]);
            const unsigned byte = word >> ((boff & 3) * 8);
            if ((x == yy) || ((byte >> (x & 7)) & 1)) {
              for (int q = lane; q < cnt; q += 64) hb[(size_t)x * TY + yy + q] = 1.0f;
              if (lane == 0) db[x] = (float)cnt;
              cnt = 0;
              --x;
            }
          }
        }
      }
    }
  }
  for (int q = lane; q < cnt; q += 64) hb[(size_t)x * TY + q] = 1.0f;
  if (lane == 0) db[x] = (float)cnt;
}

extern "C" void kernel_launch(void* const* d_in, const int* in_sizes, int n_in,
                              void* d_out, int out_size, void* d_ws, size_t ws_size,
                              hipStream_t stream) {
  const float* mel_x  = (const float*)d_in[0];
  const float* txt_x  = (const float*)d_in[1];
  const float* mel_w1 = (const float*)d_in[2];
  const float* mel_b1 = (const float*)d_in[3];
  const float* mel_w2 = (const float*)d_in[4];
  const float* mel_b2 = (const float*)d_in[5];
  const float* txt_w1 = (const float*)d_in[6];
  const float* txt_b1 = (const float*)d_in[7];
  const float* txt_w2 = (const float*)d_in[8];
  const float* txt_b2 = (const float*)d_in[9];
  const float* wq     = (const float*)d_in[10];
  const float* bq     = (const float*)d_in[11];
  const float* wk     = (const float*)d_in[12];
  const float* bk     = (const float*)d_in[13];
  const int*   xl     = (const int*)d_in[14];
  const int*   yl     = (const int*)d_in[15];

  char* wsb = (char*)d_ws;
  constexpr size_t MXH   = 0;
  constexpr size_t MXL   = MXH   + 4915200;
  constexpr size_t TXH   = MXL   + 4915200;
  constexpr size_t TXL   = TXH   + 6553600;
  constexpr size_t KTF   = TXH;
  constexpr size_t WFMH  = TXL   + 6553600;
  constexpr size_t WFML  = WFMH  + 2949120;
  constexpr size_t WFTH  = WFML  + 2949120;
  constexpr size_t WFTL  = WFTH  + 1769472;
  constexpr size_t B2M   = WFTL  + 1769472;
  constexpr size_t B2T   = B2M   + 2048;
  constexpr size_t HH    = B2T   + 2048;
  constexpr size_t HL    = HH    + 39321600;
  constexpr size_t BITS  = MXH;              // 16*102400 = 1.6MB (aliases dead mel splits)
  constexpr size_t SCR   = HL    + 39321600;
  constexpr size_t W1MH  = SCR;
  constexpr size_t W1ML  = W1MH  + 1474560;
  constexpr size_t W1TH  = W1ML  + 1474560;
  constexpr size_t W1TL  = W1TH  + 4718592;
  constexpr size_t WQH   = W1TL  + 4718592;
  constexpr size_t WQL   = WQH   + 294912;
  constexpr size_t WKH   = WQL   + 294912;
  constexpr size_t WKL   = WKH   + 294912;
  constexpr size_t W2TMH = WKL   + 294912;
  constexpr size_t W2TML = W2TMH + 2949120;
  constexpr size_t W2TTH = W2TML + 2949120;
  constexpr size_t W2TTL = W2TTH + 1769472;
  constexpr size_t QF    = SCR;

  float* out = (float*)d_out;
  float* o_attn = out;
  float* o_logp = out + (size_t)10240000;
  float* o_hard = out + (size_t)20480000;
  float* o_dur  = out + (size_t)30720000;

  hipMemsetAsync(o_hard, 0, (size_t)(10240000 + 6400) * sizeof(float), stream);

  split_pad_k<<<9600, 256, 0, stream>>>(mel_x, (__bf16*)(wsb + MXH), (__bf16*)(wsb + MXL), 80, 96, 2457600L);
  split_pad_k<<<12800, 256, 0, stream>>>(txt_x, (__bf16*)(wsb + TXH), (__bf16*)(wsb + TXL), 512, 512, 3276800L);
  wsplit_k<<<2880, 256, 0, stream>>>(mel_w1, (__bf16*)(wsb + W1MH), (__bf16*)(wsb + W1ML), 80, 5, 96, 737280L);
  wsplit_k<<<9216, 256, 0, stream>>>(txt_w1, (__bf16*)(wsb + W1TH), (__bf16*)(wsb + W1TL), 512, 3, 512, 2359296L);
  wsplit_k<<<576, 256, 0, stream>>>(wq, (__bf16*)(wsb + WQH), (__bf16*)(wsb + WQL), 384, 1, 384, 147456L);
  wsplit_k<<<576, 256, 0, stream>>>(wk, (__bf16*)(wsb + WKH), (__bf16*)(wsb + WKL), 384, 1, 384, 147456L);
  tsplit_k<<<5760, 256, 0, stream>>>(mel_w2, (__bf16*)(wsb + W2TMH), (__bf16*)(wsb + W2TML), 3840, 1474560L);
  tsplit_k<<<3456, 256, 0, stream>>>(txt_w2, (__bf16*)(wsb + W2TTH), (__bf16*)(wsb + W2TTL), 2304, 884736L);
  fold_mfma<5><<<dim3(60, 3), 256, 0, stream>>>(
      (const __bf16*)(wsb + W2TMH), (const __bf16*)(wsb + W2TML),
      (const __bf16*)(wsb + WQH), (const __bf16*)(wsb + WQL),
      (__bf16*)(wsb + WFMH), (__bf16*)(wsb + WFML));
  fold_mfma<3><<<dim3(36, 3), 256, 0, stream>>>(
      (const __bf16*)(wsb + W2TTH), (const __bf16*)(wsb + W2TTL),
      (const __bf16*)(wsb + WKH), (const __bf16*)(wsb + WKL),
      (__bf16*)(wsb + WFTH), (__bf16*)(wsb + WFTL));
  fold_bias_k<<<1, 384, 0, stream>>>(wq, mel_b2, (float*)(wsb + B2M));
  fold_bias_k<<<1, 384, 0, stream>>>(wk, txt_b2, (float*)(wsb + B2T));

  // text pipeline: conv1 -> conv2(folded) writes kT directly
  conv1_mfma<512, 3, 400><<<dim3(4, 12, B), 256, 0, stream>>>(
      (const __bf16*)(wsb + TXH), (const __bf16*)(wsb + TXL),
      (const __bf16*)(wsb + W1TH), (const __bf16*)(wsb + W1TL),
      txt_b1, xl, (__bf16*)(wsb + HH), (__bf16*)(wsb + HL));
  conv2_mfma<3, 400, true><<<dim3(4, 2, B), 256, 0, stream>>>(
      (const __bf16*)(wsb + HH), (const __bf16*)(wsb + HL),
      (const __bf16*)(wsb + WFTH), (const __bf16*)(wsb + WFTL),
      (const float*)(wsb + B2T), bk, xl, (float*)(wsb + KTF));

  // mel pipeline: conv1 -> conv2(folded) writes q directly
  conv1_mfma<96, 5, 1600><<<dim3(13, 12, B), 256, 0, stream>>>(
      (const __bf16*)(wsb + MXH), (const __bf16*)(wsb + MXL),
      (const __bf16*)(wsb + W1MH), (const __bf16*)(wsb + W1ML),
      mel_b1, yl, (__bf16*)(wsb + HH), (__bf16*)(wsb + HL));
  conv2_mfma<5, 1600, false><<<dim3(13, 2, B), 256, 0, stream>>>(
      (const __bf16*)(wsb + HH), (const __bf16*)(wsb + HL),
      (const __bf16*)(wsb + WFMH), (const __bf16*)(wsb + WFML),
      (const float*)(wsb + B2M), bq, yl, (float*)(wsb + QF));

  // attention + MAS (split fwd / bt for attribution)
  scores_k<<<dim3(100, B), 512, 0, stream>>>(
      (const float*)(wsb + QF), (const float*)(wsb + KTF), xl, yl, o_attn, o_logp);
  mas_fwd<<<B, 256, 0, stream>>>(o_logp, xl, yl, (unsigned char*)(wsb + BITS));
  mas_bt<<<B, 64, 0, stream>>>((const unsigned char*)(wsb + BITS), xl, yl, o_hard, o_dur);
}